// Round 6
// baseline (81.934 us; speedup 1.0000x reference)
//
#include <hip/hip_runtime.h>

// PopulationAttention: out = (Q K^T / sqrt(64)) @ (V * x)
// No softmax => associativity: out = Q @ M, M = K^T @ (V*x) / 8  (64x64 per head)
// B=4, H=16, N=2048, D=64  -> BH=64 batched heads.
//
// 3 kernels, coherence via kernel boundaries only (R2: per-block
// __threadfence = 4x regression on CDNA4 non-coherent XCD L2s).
// R4 lesson: stage A was latency-bound (38.6us, 13% HBM, occ 16%) with 512
// blocks + unroll 2. Fix: 1024 blocks + unroll 4 + shfl-broadcast x.

#define BH 64
#define NROWS 2048
#define DIM 64
#define NCH 16                        // stage-A chunks/head; partial = 16 MB
#define ROWS_PER_CH (NROWS / NCH)     // 128
#define ROWS_PER_WV (ROWS_PER_CH / 4) // 32

// ---- Stage A: partial[bh][ch] = sum_{m in slice} K[m]^T (V[m]*x[m]) ----
// grid (NCH, BH), 256 threads. Wave-private contiguous 32-row slice; 8x8
// per-thread register tile; K/V stream from global (8-lane broadcast float4,
// every byte read once device-wide); zero LDS in hot loop. Fixed-order
// cross-wave LDS reduce tail -> deterministic.
__global__ __launch_bounds__(256) void popattn_kv(
    const float* __restrict__ K, const float* __restrict__ V,
    const float* __restrict__ x, float* __restrict__ partial) {
  const int ch = blockIdx.x;
  const int bh = blockIdx.y;
  const float* Kp = K + (size_t)bh * (NROWS * DIM);
  const float* Vp = V + (size_t)bh * (NROWS * DIM);
  const float* xp = x + (size_t)(bh >> 4) * NROWS;  // x is [B,1,N,1], b = bh/16

  const int t = threadIdx.x;
  const int wv = t >> 6;          // wave id 0..3
  const int l = t & 63;
  const int ti = (l >> 3) << 3;   // 8x8 tile row base (K column block)
  const int tj = (l & 7) << 3;    // 8x8 tile col base (V column block)

  const int mstart = ch * ROWS_PER_CH + wv * ROWS_PER_WV;
  // lane L holds x[mstart + (L&31)]; broadcast per-m via __shfl (no global
  // load in the hot loop).
  const float xall = xp[mstart + (l & 31)];

  float acc[8][8];
#pragma unroll
  for (int i = 0; i < 8; ++i)
#pragma unroll
    for (int j = 0; j < 8; ++j) acc[i][j] = 0.f;

#pragma unroll 4
  for (int mi = 0; mi < ROWS_PER_WV; ++mi) {
    const int m = mstart + mi;
    const float4 k0 = *(const float4*)(Kp + (size_t)m * DIM + ti);
    const float4 k1 = *(const float4*)(Kp + (size_t)m * DIM + ti + 4);
    const float4 v0 = *(const float4*)(Vp + (size_t)m * DIM + tj);
    const float4 v1 = *(const float4*)(Vp + (size_t)m * DIM + tj + 4);
    const float xv = __shfl(xall, mi);
    const float kk[8] = {k0.x, k0.y, k0.z, k0.w, k1.x, k1.y, k1.z, k1.w};
    float vw[8] = {v0.x, v0.y, v0.z, v0.w, v1.x, v1.y, v1.z, v1.w};
#pragma unroll
    for (int j = 0; j < 8; ++j) vw[j] *= xv;
#pragma unroll
    for (int i = 0; i < 8; ++i)
#pragma unroll
      for (int j = 0; j < 8; ++j) acc[i][j] += kk[i] * vw[j];
  }

  // ---- cross-wave reduce in LDS, fixed order s=0..3 (deterministic) ----
  __shared__ float smem[DIM * DIM];  // 16 KB
#pragma unroll 1
  for (int s = 0; s < 4; ++s) {
    if (wv == s) {
#pragma unroll
      for (int ii = 0; ii < 8; ++ii) {
        float* dst = &smem[(ti + ii) * DIM + tj];
        if (s == 0) {
          float4 o;
          o.x = acc[ii][0]; o.y = acc[ii][1]; o.z = acc[ii][2]; o.w = acc[ii][3];
          *(float4*)dst = o;
          o.x = acc[ii][4]; o.y = acc[ii][5]; o.z = acc[ii][6]; o.w = acc[ii][7];
          *(float4*)(dst + 4) = o;
        } else {
          float4 a = *(float4*)dst;
          a.x += acc[ii][0]; a.y += acc[ii][1]; a.z += acc[ii][2]; a.w += acc[ii][3];
          *(float4*)dst = a;
          a = *(float4*)(dst + 4);
          a.x += acc[ii][4]; a.y += acc[ii][5]; a.z += acc[ii][6]; a.w += acc[ii][7];
          *(float4*)(dst + 4) = a;
        }
      }
    }
    __syncthreads();
  }

  float* Pp = partial + ((size_t)bh * NCH + ch) * (DIM * DIM);
#pragma unroll
  for (int i = 0; i < 4; ++i) {
    const int idx = (t + 256 * i) * 4;
    *(float4*)(Pp + idx) = *(const float4*)&smem[idx];
  }
}

// ---- Stage A2: M[bh] = (sum_c partial[bh][c]) * 0.125, fixed order ----
__global__ __launch_bounds__(256) void popattn_red(
    const float* __restrict__ partial, float* __restrict__ M) {
  const int e = blockIdx.x;   // 0..3 quarter of the 64x64 matrix
  const int bh = blockIdx.y;
  const int off = e * 1024 + threadIdx.x * 4;
  const float* Pp = partial + (size_t)bh * NCH * (DIM * DIM);
  float sx = 0.f, sy = 0.f, sz = 0.f, sw = 0.f;
#pragma unroll
  for (int c = 0; c < NCH; ++c) {
    const float4 p = *(const float4*)(Pp + (size_t)c * (DIM * DIM) + off);
    sx += p.x; sy += p.y; sz += p.z; sw += p.w;
  }
  float4 o;
  o.x = sx * 0.125f; o.y = sy * 0.125f; o.z = sz * 0.125f; o.w = sw * 0.125f;
  *(float4*)(M + (size_t)bh * (DIM * DIM) + off) = o;
}

// ---- Stage B: out[bh] = Q[bh] @ M[bh].  256 rows/block, per-thread 8x8 tile,
// double-buffered Q prefetch (static indexing via even/odd unroll). ----
__global__ __launch_bounds__(256) void popattn_qm(
    const float* __restrict__ Q, const float* __restrict__ M,
    float* __restrict__ out) {
  const int ch = blockIdx.x;  // 0..7
  const int bh = blockIdx.y;
  const int row0 = ch * 256;
  const float* Qp = Q + (size_t)bh * (NROWS * DIM) + (size_t)row0 * DIM;
  float* Op = out + (size_t)bh * (NROWS * DIM) + (size_t)row0 * DIM;

  __shared__ float sM[DIM * DIM];  // 16 KB

  const int t = threadIdx.x;
  {
    const float* Mp = M + (size_t)bh * (DIM * DIM);
#pragma unroll
    for (int i = 0; i < 4; ++i) {
      const int off = i * 1024 + t * 4;
      *(float4*)&sM[off] = *(const float4*)(Mp + off);
    }
  }
  __syncthreads();

  const int r = t >> 3;         // rows r + 32*rr, rr = 0..7
  const int c8 = (t & 7) * 8;   // cols c8..c8+7

  float acc[8][8];
#pragma unroll
  for (int rr = 0; rr < 8; ++rr)
#pragma unroll
    for (int jj = 0; jj < 8; ++jj) acc[rr][jj] = 0.f;

  float4 qa[8], qb[8];
#pragma unroll
  for (int rr = 0; rr < 8; ++rr)
    qa[rr] = *(const float4*)(Qp + (size_t)(r + 32 * rr) * DIM + 0);

#pragma unroll
  for (int kg = 0; kg < 16; kg += 2) {
    // prefetch kg+1 while computing kg
#pragma unroll
    for (int rr = 0; rr < 8; ++rr)
      qb[rr] = *(const float4*)(Qp + (size_t)(r + 32 * rr) * DIM + (kg + 1) * 4);
#pragma unroll
    for (int dk = 0; dk < 4; ++dk) {
      const int k = kg * 4 + dk;
      const float4 m0 = *(const float4*)&sM[k * DIM + c8];
      const float4 m1 = *(const float4*)&sM[k * DIM + c8 + 4];
      const float mm[8] = {m0.x, m0.y, m0.z, m0.w, m1.x, m1.y, m1.z, m1.w};
#pragma unroll
      for (int rr = 0; rr < 8; ++rr) {
        const float q = (dk == 0) ? qa[rr].x : (dk == 1) ? qa[rr].y
                       : (dk == 2) ? qa[rr].z : qa[rr].w;
#pragma unroll
        for (int jj = 0; jj < 8; ++jj) acc[rr][jj] += q * mm[jj];
      }
    }
    // prefetch kg+2 while computing kg+1
    if (kg + 2 < 16) {
#pragma unroll
      for (int rr = 0; rr < 8; ++rr)
        qa[rr] = *(const float4*)(Qp + (size_t)(r + 32 * rr) * DIM + (kg + 2) * 4);
    }
#pragma unroll
    for (int dk = 0; dk < 4; ++dk) {
      const int k = (kg + 1) * 4 + dk;
      const float4 m0 = *(const float4*)&sM[k * DIM + c8];
      const float4 m1 = *(const float4*)&sM[k * DIM + c8 + 4];
      const float mm[8] = {m0.x, m0.y, m0.z, m0.w, m1.x, m1.y, m1.z, m1.w};
#pragma unroll
      for (int rr = 0; rr < 8; ++rr) {
        const float q = (dk == 0) ? qb[rr].x : (dk == 1) ? qb[rr].y
                       : (dk == 2) ? qb[rr].z : qb[rr].w;
#pragma unroll
        for (int jj = 0; jj < 8; ++jj) acc[rr][jj] += q * mm[jj];
      }
    }
  }

#pragma unroll
  for (int rr = 0; rr < 8; ++rr) {
    float4 o;
    o.x = acc[rr][0]; o.y = acc[rr][1]; o.z = acc[rr][2]; o.w = acc[rr][3];
    *(float4*)(Op + (size_t)(r + 32 * rr) * DIM + c8) = o;
    o.x = acc[rr][4]; o.y = acc[rr][5]; o.z = acc[rr][6]; o.w = acc[rr][7];
    *(float4*)(Op + (size_t)(r + 32 * rr) * DIM + c8 + 4) = o;
  }
}

extern "C" void kernel_launch(void* const* d_in, const int* in_sizes, int n_in,
                              void* d_out, int out_size, void* d_ws, size_t ws_size,
                              hipStream_t stream) {
  const float* Q = (const float*)d_in[0];
  const float* K = (const float*)d_in[1];
  const float* V = (const float*)d_in[2];
  const float* x = (const float*)d_in[3];
  float* out = (float*)d_out;
  float* partial = (float*)d_ws;  // BH*NCH*4096 floats = 16 MB
  float* Mbuf = partial + (size_t)BH * NCH * DIM * DIM;  // +1 MB

  dim3 blk(256);
  popattn_kv<<<dim3(NCH, BH), blk, 0, stream>>>(K, V, x, partial);
  popattn_red<<<dim3(4, BH), blk, 0, stream>>>(partial, Mbuf);
  popattn_qm<<<dim3(NROWS / 256, BH), blk, 0, stream>>>(Q, Mbuf, out);
}

// Round 7
// 52.507 us; speedup vs baseline: 1.5604x; 1.5604x over previous
//
#include <hip/hip_runtime.h>

// PopulationAttention: out = (Q K^T / sqrt(64)) @ (V * x)
// No softmax => associativity: out = Q @ M, M = K^T @ (V*x) / 8  (64x64 per head)
// B=4, H=16, N=2048, D=64  -> BH=64 batched heads.
//
// 3 kernels, coherence via kernel boundaries only (R2: per-block
// __threadfence = 4x regression on CDNA4 non-coherent XCD L2s).
// R5 lessons: kv streaming w/ 1024 blocks + unroll 4 is fast (~6us);
// qm manual Q-double-buffer hit 256 VGPR -> occupancy 9% -> 72us. qm must
// stay lean (<=~100 VGPR): 4x8 tile, no manual prefetch arrays.

#define BH 64
#define NROWS 2048
#define DIM 64
#define NCH 16                        // stage-A chunks/head; partial = 16 MB
#define ROWS_PER_CH (NROWS / NCH)     // 128
#define ROWS_PER_WV (ROWS_PER_CH / 4) // 32

// ---- Stage A: partial[bh][ch] = sum_{m in slice} K[m]^T (V[m]*x[m]) ----
// grid (NCH, BH), 256 threads. Wave-private contiguous 32-row slice; 8x8
// per-thread register tile; K/V stream from global (8-lane broadcast float4,
// every byte read once device-wide); zero LDS in hot loop. Fixed-order
// cross-wave LDS reduce tail -> deterministic.  [UNCHANGED from R5]
__global__ __launch_bounds__(256) void popattn_kv(
    const float* __restrict__ K, const float* __restrict__ V,
    const float* __restrict__ x, float* __restrict__ partial) {
  const int ch = blockIdx.x;
  const int bh = blockIdx.y;
  const float* Kp = K + (size_t)bh * (NROWS * DIM);
  const float* Vp = V + (size_t)bh * (NROWS * DIM);
  const float* xp = x + (size_t)(bh >> 4) * NROWS;  // x is [B,1,N,1], b = bh/16

  const int t = threadIdx.x;
  const int wv = t >> 6;          // wave id 0..3
  const int l = t & 63;
  const int ti = (l >> 3) << 3;   // 8x8 tile row base (K column block)
  const int tj = (l & 7) << 3;    // 8x8 tile col base (V column block)

  const int mstart = ch * ROWS_PER_CH + wv * ROWS_PER_WV;
  // lane L holds x[mstart + (L&31)]; broadcast per-m via __shfl.
  const float xall = xp[mstart + (l & 31)];

  float acc[8][8];
#pragma unroll
  for (int i = 0; i < 8; ++i)
#pragma unroll
    for (int j = 0; j < 8; ++j) acc[i][j] = 0.f;

#pragma unroll 4
  for (int mi = 0; mi < ROWS_PER_WV; ++mi) {
    const int m = mstart + mi;
    const float4 k0 = *(const float4*)(Kp + (size_t)m * DIM + ti);
    const float4 k1 = *(const float4*)(Kp + (size_t)m * DIM + ti + 4);
    const float4 v0 = *(const float4*)(Vp + (size_t)m * DIM + tj);
    const float4 v1 = *(const float4*)(Vp + (size_t)m * DIM + tj + 4);
    const float xv = __shfl(xall, mi);
    const float kk[8] = {k0.x, k0.y, k0.z, k0.w, k1.x, k1.y, k1.z, k1.w};
    float vw[8] = {v0.x, v0.y, v0.z, v0.w, v1.x, v1.y, v1.z, v1.w};
#pragma unroll
    for (int j = 0; j < 8; ++j) vw[j] *= xv;
#pragma unroll
    for (int i = 0; i < 8; ++i)
#pragma unroll
      for (int j = 0; j < 8; ++j) acc[i][j] += kk[i] * vw[j];
  }

  // ---- cross-wave reduce in LDS, fixed order s=0..3 (deterministic) ----
  __shared__ float smem[DIM * DIM];  // 16 KB
#pragma unroll 1
  for (int s = 0; s < 4; ++s) {
    if (wv == s) {
#pragma unroll
      for (int ii = 0; ii < 8; ++ii) {
        float* dst = &smem[(ti + ii) * DIM + tj];
        if (s == 0) {
          float4 o;
          o.x = acc[ii][0]; o.y = acc[ii][1]; o.z = acc[ii][2]; o.w = acc[ii][3];
          *(float4*)dst = o;
          o.x = acc[ii][4]; o.y = acc[ii][5]; o.z = acc[ii][6]; o.w = acc[ii][7];
          *(float4*)(dst + 4) = o;
        } else {
          float4 a = *(float4*)dst;
          a.x += acc[ii][0]; a.y += acc[ii][1]; a.z += acc[ii][2]; a.w += acc[ii][3];
          *(float4*)dst = a;
          a = *(float4*)(dst + 4);
          a.x += acc[ii][4]; a.y += acc[ii][5]; a.z += acc[ii][6]; a.w += acc[ii][7];
          *(float4*)(dst + 4) = a;
        }
      }
    }
    __syncthreads();
  }

  float* Pp = partial + ((size_t)bh * NCH + ch) * (DIM * DIM);
#pragma unroll
  for (int i = 0; i < 4; ++i) {
    const int idx = (t + 256 * i) * 4;
    *(float4*)(Pp + idx) = *(const float4*)&smem[idx];
  }
}

// ---- Stage A2: M[bh] = (sum_c partial[bh][c]) * 0.125, fixed order ----
__global__ __launch_bounds__(256) void popattn_red(
    const float* __restrict__ partial, float* __restrict__ M) {
  const int e = blockIdx.x;   // 0..3 quarter of the 64x64 matrix
  const int bh = blockIdx.y;
  const int off = e * 1024 + threadIdx.x * 4;
  const float* Pp = partial + (size_t)bh * NCH * (DIM * DIM);
  float sx = 0.f, sy = 0.f, sz = 0.f, sw = 0.f;
#pragma unroll
  for (int c = 0; c < NCH; ++c) {
    const float4 p = *(const float4*)(Pp + (size_t)c * (DIM * DIM) + off);
    sx += p.x; sy += p.y; sz += p.z; sw += p.w;
  }
  float4 o;
  o.x = sx * 0.125f; o.y = sy * 0.125f; o.z = sz * 0.125f; o.w = sw * 0.125f;
  *(float4*)(M + (size_t)bh * (DIM * DIM) + off) = o;
}

// ---- Stage B: out[bh] = Q[bh] @ M[bh].  128 rows/block, per-thread 4x8 tile.
// Lean on VGPRs (acc 32 + qv 16): let the compiler schedule Q loads. ----
__global__ __launch_bounds__(256) void popattn_qm(
    const float* __restrict__ Q, const float* __restrict__ M,
    float* __restrict__ out) {
  const int ch = blockIdx.x;  // 0..15
  const int bh = blockIdx.y;
  const int row0 = ch * 128;
  const float* Qp = Q + (size_t)bh * (NROWS * DIM) + (size_t)row0 * DIM;
  float* Op = out + (size_t)bh * (NROWS * DIM) + (size_t)row0 * DIM;

  __shared__ float sM[DIM * DIM];  // 16 KB

  const int t = threadIdx.x;
  {
    const float* Mp = M + (size_t)bh * (DIM * DIM);
#pragma unroll
    for (int i = 0; i < 4; ++i) {
      const int off = i * 1024 + t * 4;
      *(float4*)&sM[off] = *(const float4*)(Mp + off);
    }
  }
  __syncthreads();

  const int r = t >> 3;         // rows r + 32*rr, rr = 0..3
  const int c8 = (t & 7) * 8;   // cols c8..c8+7

  float acc[4][8];
#pragma unroll
  for (int rr = 0; rr < 4; ++rr)
#pragma unroll
    for (int jj = 0; jj < 8; ++jj) acc[rr][jj] = 0.f;

#pragma unroll 4
  for (int kg = 0; kg < 16; ++kg) {
    float4 qv[4];
#pragma unroll
    for (int rr = 0; rr < 4; ++rr)
      qv[rr] = *(const float4*)(Qp + (size_t)(r + 32 * rr) * DIM + kg * 4);
#pragma unroll
    for (int dk = 0; dk < 4; ++dk) {
      const int k = kg * 4 + dk;
      const float4 m0 = *(const float4*)&sM[k * DIM + c8];
      const float4 m1 = *(const float4*)&sM[k * DIM + c8 + 4];
      const float mm[8] = {m0.x, m0.y, m0.z, m0.w, m1.x, m1.y, m1.z, m1.w};
#pragma unroll
      for (int rr = 0; rr < 4; ++rr) {
        const float q = (dk == 0) ? qv[rr].x : (dk == 1) ? qv[rr].y
                       : (dk == 2) ? qv[rr].z : qv[rr].w;
#pragma unroll
        for (int jj = 0; jj < 8; ++jj) acc[rr][jj] += q * mm[jj];
      }
    }
  }

#pragma unroll
  for (int rr = 0; rr < 4; ++rr) {
    float4 o;
    o.x = acc[rr][0]; o.y = acc[rr][1]; o.z = acc[rr][2]; o.w = acc[rr][3];
    *(float4*)(Op + (size_t)(r + 32 * rr) * DIM + c8) = o;
    o.x = acc[rr][4]; o.y = acc[rr][5]; o.z = acc[rr][6]; o.w = acc[rr][7];
    *(float4*)(Op + (size_t)(r + 32 * rr) * DIM + c8 + 4) = o;
  }
}

extern "C" void kernel_launch(void* const* d_in, const int* in_sizes, int n_in,
                              void* d_out, int out_size, void* d_ws, size_t ws_size,
                              hipStream_t stream) {
  const float* Q = (const float*)d_in[0];
  const float* K = (const float*)d_in[1];
  const float* V = (const float*)d_in[2];
  const float* x = (const float*)d_in[3];
  float* out = (float*)d_out;
  float* partial = (float*)d_ws;  // BH*NCH*4096 floats = 16 MB
  float* Mbuf = partial + (size_t)BH * NCH * DIM * DIM;  // +1 MB

  dim3 blk(256);
  popattn_kv<<<dim3(NCH, BH), blk, 0, stream>>>(K, V, x, partial);
  popattn_red<<<dim3(4, BH), blk, 0, stream>>>(partial, Mbuf);
  popattn_qm<<<dim3(NROWS / 128, BH), blk, 0, stream>>>(Q, Mbuf, out);
}